// Round 10
// baseline (85.188 us; speedup 1.0000x reference)
//
#include <hip/hip_runtime.h>
#include <math.h>

#define M_CHECKS 63
#define N_CODE   127
#define ROW_W    8
#define BATCH    4096
#define NITER    5
#define BIGF     1e10f
#define MAXD     16   // max column degree bound; proven sufficient (rounds 3-9 passed)

// ---------------------------------------------------------------------------
// Setup kernel (1 block, 1 wave): builds per-edge tables once.
//   tbl[i*16 + p]     = column of edge p of check i
//   tbl[i*16 + 8 + p] = cvals word offset: (slot/2)*256 + 2*col + (slot&1)
//   tbl[63*16]        = spairs = ceil(max_column_degree / 2)
// Slot of edge (i,c) = #checks i' < i containing c (popcount of column mask),
// a bijective per-column slot assignment (order within a column is irrelevant:
// the column phase sums all slots).
// ---------------------------------------------------------------------------
__global__ void build_tables(const int* __restrict__ H, int* __restrict__ tbl) {
    __shared__ int                sidx[M_CHECKS * ROW_W];
    __shared__ unsigned long long cmask[128];

    const int lane = threadIdx.x & 63;
    const int c0 = lane;
    const int c1 = lane + 64;                      // lane 63 -> 127: pad column
    unsigned long long cm0 = 0ull, cm1 = 0ull;
    const unsigned long long below =
        (lane == 0) ? 0ull : ((~0ull) >> (64 - lane));

    for (int k = 0; k < 4; ++k) {                  // 4 chunks x 16 rows
        int a[16], b[16];
        #pragma unroll
        for (int r = 0; r < 16; ++r) {
            int i = k * 16 + r;
            a[r] = (i < M_CHECKS) ? H[i * N_CODE + c0] : 0;
            b[r] = (i < M_CHECKS && c1 < N_CODE) ? H[i * N_CODE + c1] : 0;
        }
        #pragma unroll
        for (int r = 0; r < 16; ++r) {
            int i = k * 16 + r;
            if (i < M_CHECKS) {
                unsigned long long m0 = __ballot(a[r] != 0);
                unsigned long long m1 = __ballot(b[r] != 0);
                if (a[r]) {
                    int pos = __popcll(m0 & below);
                    if (pos < ROW_W) sidx[i * ROW_W + pos] = c0;
                }
                if (b[r]) {
                    int pos = __popcll(m0) + __popcll(m1 & below);
                    if (pos < ROW_W) sidx[i * ROW_W + pos] = c1;
                }
                cm0 |= a[r] ? (1ull << i) : 0ull;
                cm1 |= b[r] ? (1ull << i) : 0ull;
            }
        }
    }
    cmask[c0] = cm0;
    cmask[c1 & 127] = cm1;                         // lane63 writes pad col 127 = 0

    int deg = max(__popcll(cm0), __popcll(cm1));
    #pragma unroll
    for (int off = 32; off; off >>= 1)
        deg = max(deg, __shfl_xor(deg, off, 64));

    // wave-own LDS writes -> reads: in-order DS pipe; pin compiler order only
    asm volatile("" ::: "memory");
    __builtin_amdgcn_sched_barrier(0);

    if (lane < M_CHECKS) {
        const unsigned long long ibelow = (1ull << lane) - 1;  // checks before i
        #pragma unroll
        for (int p = 0; p < ROW_W; ++p) {
            int c    = sidx[lane * ROW_W + p];
            int slot = (int)__popcll(cmask[c] & ibelow);       // < MAXD, proven
            tbl[lane * 16 + p]     = c;
            tbl[lane * 16 + 8 + p] = (slot >> 1) * 256 + 2 * c + (slot & 1);
        }
    }
    if (lane == 0) tbl[M_CHECKS * 16] = (deg + 1) >> 1;        // spairs
}

// ---------------------------------------------------------------------------
// Main kernel: one wave = one batch row. NO __syncthreads anywhere: tables
// are register-resident (loaded from tbl), cur[w]/cvals[w] strictly
// wave-private. VALU-lean check phase:
//   * proc=(|x|==0)?BIG:|x| select DROPPED: any zero entry forces sprod=0,
//     which zeroes every cv of the check in BOTH ref and ours -> identical.
//   * sign product via bit parity (xor of float bits) + one zero flag; final
//     sign applied with a single v_xor_b32 on the magnitude norm*upd.
// ---------------------------------------------------------------------------
__launch_bounds__(256, 4)
__global__ void nms_decode(const float* __restrict__ soft,
                           const int*   __restrict__ labels,
                           const float* __restrict__ normalizor,
                           const int*   __restrict__ tbl,
                           float*       __restrict__ out) {
    __shared__ float cur[4][128];                // per-wave row state
    __shared__ float cvals[4][MAXD / 2][128][2]; // per-wave paired-slot edge values

    const int tid  = threadIdx.x;
    const int w    = tid >> 6;
    const int lane = tid & 63;
    const int row  = blockIdx.x * 4 + w;

    // zero OWN wave's cvals (8 KB/wave = 8 float4 per lane)
    {
        float4* z = (float4*)&cvals[w][0][0][0];
        #pragma unroll
        for (int t = 0; t < 8; ++t)
            z[lane + t * 64] = make_float4(0.f, 0.f, 0.f, 0.f);
    }

    // register-resident edge tables (coalesced dwordx4; lane 63 values unused)
    int ec[ROW_W], widx[ROW_W];
    {
        const int4* t4 = (const int4*)(tbl + lane * 16);
        int4 A = t4[0], B = t4[1], C = t4[2], D = t4[3];
        ec[0] = A.x; ec[1] = A.y; ec[2] = A.z; ec[3] = A.w;
        ec[4] = B.x; ec[5] = B.y; ec[6] = B.z; ec[7] = B.w;
        widx[0] = C.x; widx[1] = C.y; widx[2] = C.z; widx[3] = C.w;
        widx[4] = D.x; widx[5] = D.y; widx[6] = D.z; widx[7] = D.w;
    }
    const int spairs = __builtin_amdgcn_readfirstlane(tbl[M_CHECKS * 16]);

    const float norm = log1pf(expf(normalizor[0]));  // softplus
    float* outLabels = out + (size_t)(NITER + 1) * BATCH * N_CODE;
    float* const cvw = &cvals[w][0][0][0];

    // ---- load state + emit outs[0] and labels ----
    const int j0 = lane;
    const int j1 = lane + 64;                    // lane 63 -> 127: pad column
    float x0, x1 = 0.0f;
    {
        const size_t base = (size_t)row * N_CODE;
        x0 = soft[base + j0];
        cur[w][j0] = x0;
        out[base + j0] = x0;                                   // outs[0]
        outLabels[base + j0] = (float)labels[base + j0];       // labels as 0.0/1.0
        if (lane < 63) {
            x1 = soft[base + j1];
            cur[w][j1] = x1;
            out[base + j1] = x1;
            outLabels[base + j1] = (float)labels[base + j1];
        }
    }
    // cur writes -> first gather: in-order DS pipe; pin compiler order only.
    asm volatile("" ::: "memory");
    __builtin_amdgcn_sched_barrier(0);

    for (int it = 0; it < NITER; ++it) {
        // ---- check phase ----
        if (lane < M_CHECKS) {
            float v[ROW_W];
            #pragma unroll
            for (int p = 0; p < ROW_W; ++p) v[p] = cur[w][ec[p]];

            float m1 = BIGF, m2 = BIGF;
            unsigned xb = 0u;          // xor of float bits; bit31 = neg parity
            bool anyz = false;         // any exact zero -> check contributes 0
            #pragma unroll
            for (int p = 0; p < ROW_W; ++p) {
                float x = v[p];
                xb ^= __float_as_uint(x);
                anyz |= (x == 0.0f);
                float av = fabsf(x);
                if (av < m1) { m2 = m1; m1 = av; }
                else if (av < m2) { m2 = av; }
            }
            const float    nsp = anyz ? 0.0f : norm;
            const unsigned par = xb & 0x80000000u;
            #pragma unroll
            for (int p = 0; p < ROW_W; ++p) {
                float x   = v[p];
                float upd = (fabsf(x) == m1) ? m2 : m1;  // exact-equality rule
                unsigned sb = (__float_as_uint(x) & 0x80000000u) ^ par;
                cvw[widx[p]] = __uint_as_float(__float_as_uint(nsp * upd) ^ sb);
            }
        }
        // scatter-writes -> strip-reads: ordered by the in-order DS pipe.
        asm volatile("" ::: "memory");
        __builtin_amdgcn_sched_barrier(0);

        // ---- column phase: b64 strip sums over live slot pairs only ----
        const float2* cv2 = (const float2*)cvw;
        float acc0 = 0.0f, acc1 = 0.0f;
        for (int e = 0; e < spairs; ++e) {
            float2 a = cv2[e * 128 + j0];   // 1-address b64, conflict-free
            float2 b = cv2[e * 128 + j1];
            acc0 += a.x + a.y;
            acc1 += b.x + b.y;
        }
        x0 += acc0;
        x1 += acc1;

        cur[w][j0] = x0;     // unconditional pair: merges to write2st64
        cur[w][j1] = x1;     // j1=127 is a harmless pad slot for lane 63

        const size_t obase = (size_t)(it + 1) * BATCH * N_CODE + (size_t)row * N_CODE;
        out[obase + j0] = x0;
        if (lane < 63) out[obase + j1] = x1;

        // cur-writes -> next-iter gathers: ordered by the in-order DS pipe.
        asm volatile("" ::: "memory");
        __builtin_amdgcn_sched_barrier(0);
    }
}

extern "C" void kernel_launch(void* const* d_in, const int* in_sizes, int n_in,
                              void* d_out, int out_size, void* d_ws, size_t ws_size,
                              hipStream_t stream) {
    const float* soft       = (const float*)d_in[0];
    const int*   labels     = (const int*)d_in[1];
    const int*   H          = (const int*)d_in[2];
    const float* normalizor = (const float*)d_in[3];
    float*       out        = (float*)d_out;
    int*         tbl        = (int*)d_ws;   // 63*16+1 ints ~ 4 KB

    build_tables<<<1, 64, 0, stream>>>(H, tbl);
    nms_decode<<<BATCH / 4, 256, 0, stream>>>(soft, labels, normalizor, tbl, out);
}

// Round 11
// 83.078 us; speedup vs baseline: 1.0254x; 1.0254x over previous
//
#include <hip/hip_runtime.h>
#include <math.h>

#define M_CHECKS 63
#define N_CODE   127
#define ROW_W    8
#define BATCH    4096
#define NITER    5
#define MAXD     16   // max column degree bound; proven sufficient (rounds 3-10 passed)

// Flooding NMS decoder. One wave = one batch row. Row state (127 floats) lives
// in TWO REGISTERS per lane (x0 = cols 0-63, x1 = cols 64-127 across lanes).
//   check phase : lane i (<63) gathers its 8 column values via __shfl
//                 (ds_bpermute crossbar: conflict-free, no LDS cur array, no
//                 write->read coupling at the loop head), computes
//                 (min1,min2,sign-parity), scatters finished contributions
//                 cv = norm*upd*sprod*s into paired-slot cvals.
//   column phase: conflict-free b64 strip sums over live slot pairs; state
//                 update is a pure register add.
// Rationale: rounds 7-10 proved DS op-count, VALU count, and preamble are all
// off the critical path; the remaining cost is the per-iteration latency chain
// through LDS cur + birthday bank conflicts on the random-column gathers.
// Both are removed here. Scatter->strip ordering relies on the wave-in-order
// DS pipe (proven rounds 6-10).
__launch_bounds__(256, 4)
__global__ void nms_decode(const float* __restrict__ soft,
                           const int*   __restrict__ labels,
                           const int*   __restrict__ H,
                           const float* __restrict__ normalizor,
                           float*       __restrict__ out) {
    __shared__ float cvals[4][MAXD / 2][128][2];   // per-wave paired-slot edge values (32 KB)
    __shared__ int   sidx[64 * ROW_W];             // check -> columns (row 63 = zeros)
    __shared__ unsigned long long cmaskp[4][128];  // per-wave partial column masks (4 KB)

    const int tid  = threadIdx.x;
    const int w    = tid >> 6;
    const int lane = tid & 63;
    const int row  = blockIdx.x * 4 + w;

    // zero OWN wave's cvals (pads must read 0.0 forever) — wave-private, no sync needed
    {
        float4* z = (float4*)&cvals[w][0][0][0];
        #pragma unroll
        for (int t = 0; t < 8; ++t)
            z[lane + t * 64] = make_float4(0.f, 0.f, 0.f, 0.f);
    }

    // ---- ballot build: sidx rows w::4 + this wave's partial column masks ----
    {
        const unsigned long long below =
            (lane == 0) ? 0ull : ((~0ull) >> (64 - lane));
        const int c0 = lane;
        const int c1 = lane + 64;                  // lane 63 -> 127: pad column
        unsigned long long cm0 = 0ull, cm1 = 0ull;
        for (int i = w; i < M_CHECKS; i += 4) {
            const int b0 = (H[i * N_CODE + c0] != 0) ? 1 : 0;
            const int b1 = (c1 < N_CODE) ? ((H[i * N_CODE + c1] != 0) ? 1 : 0) : 0;
            unsigned long long m0 = __ballot(b0);
            unsigned long long m1 = __ballot(b1);
            if (b0) {
                int pos = __popcll(m0 & below);
                if (pos < ROW_W) sidx[i * ROW_W + pos] = c0;
            }
            if (b1) {
                int pos = __popcll(m0) + __popcll(m1 & below);
                if (pos < ROW_W) sidx[i * ROW_W + pos] = c1;
            }
            cm0 |= b0 ? (1ull << i) : 0ull;
            cm1 |= b1 ? (1ull << i) : 0ull;
        }
        cmaskp[w][c0] = cm0;
        cmaskp[w][c1 & 127] = cm1;                 // lane 63 writes pad col 127 = 0
        if (w == 3 && lane < ROW_W) sidx[M_CHECKS * ROW_W + lane] = 0;  // row 63 zeros
    }
    __syncthreads();   // sidx + cmaskp visible

    // ---- register tables: columns + scatter offsets via popcount slots ----
    // slot(i,c) = #checks i' < i containing c  (bijective per column; order
    // within a column is irrelevant — the column phase sums all slots).
    int ec[ROW_W], widx[ROW_W];
    {
        #pragma unroll
        for (int p = 0; p < ROW_W; ++p) ec[p] = sidx[lane * ROW_W + p];
        const unsigned long long ibelow = (1ull << lane) - 1;
        #pragma unroll
        for (int p = 0; p < ROW_W; ++p) {
            int c = ec[p];
            unsigned long long cm = cmaskp[0][c] | cmaskp[1][c]
                                  | cmaskp[2][c] | cmaskp[3][c];
            int slot = (int)__popcll(cm & ibelow);            // < MAXD, proven
            widx[p] = (slot >> 1) * 256 + 2 * c + (slot & 1);
        }
    }

    // ---- wave-uniform max column degree -> live slot-pair count ----
    int spairs;
    {
        const unsigned long long mj0 = cmaskp[0][lane] | cmaskp[1][lane]
                                     | cmaskp[2][lane] | cmaskp[3][lane];
        const unsigned long long mj1 = cmaskp[0][lane + 64] | cmaskp[1][lane + 64]
                                     | cmaskp[2][lane + 64] | cmaskp[3][lane + 64];
        int deg = max(__popcll(mj0), __popcll(mj1));
        #pragma unroll
        for (int off = 32; off; off >>= 1)
            deg = max(deg, __shfl_xor(deg, off, 64));
        spairs = min((deg + 1) >> 1, MAXD / 2);
    }

    const float norm = log1pf(expf(normalizor[0]));  // softplus
    float* outLabels = out + (size_t)(NITER + 1) * BATCH * N_CODE;
    float* const cvw = &cvals[w][0][0][0];
    const float2* const cv2 = (const float2*)cvw;

    // ---- load state into registers + emit outs[0] and labels ----
    const int j0 = lane;
    const int j1 = lane + 64;                      // lane 63 -> 127: pad column
    float x0, x1 = 0.0f;
    {
        const size_t base = (size_t)row * N_CODE;
        x0 = soft[base + j0];
        out[base + j0] = x0;                                   // outs[0]
        outLabels[base + j0] = (float)labels[base + j0];       // labels as 0.0/1.0
        if (lane < 63) {
            x1 = soft[base + j1];
            out[base + j1] = x1;
            outLabels[base + j1] = (float)labels[base + j1];
        }
    }

    for (int it = 0; it < NITER; ++it) {
        // ---- gather via register crossbar (ALL 64 lanes active: __shfl /
        //      ds_bpermute from an inactive source lane is undefined) ----
        float v[ROW_W];
        #pragma unroll
        for (int p = 0; p < ROW_W; ++p) {
            const int c  = ec[p];                  // loop-invariant: addr calc hoisted
            const float lo = __shfl(x0, c, 64);    // srcLane mod 64
            const float hi = __shfl(x1, c, 64);
            v[p] = (c < 64) ? lo : hi;
        }

        // ---- check compute (VALU-lean; lane 63 computes garbage, writes nothing)
        float m1 = 1e30f, m2 = 1e30f;
        unsigned xb = 0u;              // xor of float bits; bit31 = sign parity
        bool anyz = false;             // any exact zero -> check contributes 0
        #pragma unroll
        for (int p = 0; p < ROW_W; ++p) {
            const float x = v[p];
            xb ^= __float_as_uint(x);
            anyz |= (x == 0.0f);
            const float av = fabsf(x);
            if (av < m1) { m2 = m1; m1 = av; }
            else if (av < m2) { m2 = av; }
        }
        const float    nsp = anyz ? 0.0f : norm;   // zero entry => sprod = 0 (ref rule)
        const unsigned par = xb & 0x80000000u;

        if (lane < M_CHECKS) {
            #pragma unroll
            for (int p = 0; p < ROW_W; ++p) {
                const float    x   = v[p];
                const float    upd = (fabsf(x) == m1) ? m2 : m1;  // exact-equality rule
                const unsigned sb  = (__float_as_uint(x) & 0x80000000u) ^ par;
                cvw[widx[p]] = __uint_as_float(__float_as_uint(nsp * upd) ^ sb);
            }
        }
        // scatter-writes -> strip-reads: ordered by the wave-in-order DS pipe;
        // pin compiler program order only (zero instructions emitted).
        asm volatile("" ::: "memory");
        __builtin_amdgcn_sched_barrier(0);

        // ---- column phase: b64 strip sums over live slot pairs; pure
        //      register state update ----
        float acc0 = 0.0f, acc1 = 0.0f;
        for (int e = 0; e < spairs; ++e) {
            const float2 a = cv2[e * 128 + j0];    // 1-address b64, conflict-free
            const float2 b = cv2[e * 128 + j1];
            acc0 += a.x + a.y;
            acc1 += b.x + b.y;
        }
        x0 += acc0;
        x1 += acc1;

        const size_t obase = (size_t)(it + 1) * BATCH * N_CODE + (size_t)row * N_CODE;
        out[obase + j0] = x0;
        if (lane < 63) out[obase + j1] = x1;
        // no cur write, no drain: next gather reads x0/x1 registers directly.
    }
}

extern "C" void kernel_launch(void* const* d_in, const int* in_sizes, int n_in,
                              void* d_out, int out_size, void* d_ws, size_t ws_size,
                              hipStream_t stream) {
    const float* soft       = (const float*)d_in[0];
    const int*   labels     = (const int*)d_in[1];
    const int*   H          = (const int*)d_in[2];
    const float* normalizor = (const float*)d_in[3];
    float*       out        = (float*)d_out;

    nms_decode<<<BATCH / 4, 256, 0, stream>>>(soft, labels, H, normalizor, out);
}